// Round 1
// baseline (1508.103 us; speedup 1.0000x reference)
//
#include <hip/hip_runtime.h>
#include <stdint.h>

#define NT 131072   // tokens
#define DM 2048     // d_model
#define DH 256      // d_hid
#define NH 16       // heads
#define WIN 64      // window

typedef unsigned short u16;
typedef unsigned int u32;
typedef __attribute__((ext_vector_type(8))) short bf16x8;   // 8 bf16 = 4 VGPRs
typedef __attribute__((ext_vector_type(4))) float f32x4;

__device__ __forceinline__ u16 f2bf(float f) {
  u32 u = __builtin_bit_cast(u32, f);
  u32 r = u + 0x7FFFu + ((u >> 16) & 1u);   // RNE
  return (u16)(r >> 16);
}

__device__ __forceinline__ void async16(const void* g, void* l) {
  __builtin_amdgcn_global_load_lds((const __attribute__((address_space(1))) u32*)g,
                                   (__attribute__((address_space(3))) u32*)l, 16, 0, 0);
}

// ---------------------------------------------------------------------------
// prep: w1 (2048x256 f32) -> w1t bf16 [256][2048]; queries/values -> qv bf16 [32][256]
__global__ __launch_bounds__(256) void prep_kernel(const float* __restrict__ w1,
                                                   const float* __restrict__ qin,
                                                   const float* __restrict__ vin,
                                                   u16* __restrict__ w1t,
                                                   u16* __restrict__ qv) {
  const int tid = blockIdx.x * 256 + threadIdx.x;   // grid 2048*256 = 524288 exact
  const int n = tid >> 11;
  const int k = tid & 2047;
  w1t[tid] = f2bf(w1[(size_t)k * DH + n]);
  if (tid < 32 * 256) {
    const int r = tid >> 8, c = tid & 255;
    float val = (r < 16) ? qin[r * 256 + c] : vin[(r - 16) * 256 + c];
    qv[tid] = f2bf(val);
  }
}

// ---------------------------------------------------------------------------
// fused_gemm: per block BM=64 tokens x full DH=256.
//   main loop: y = relu(x@w1 + b1) via mfma_f32_16x16x32_bf16, BK=32
//   epilogue:  y (bf16, LDS) @ [q;v]^T via second MFMA -> e=exp(logit), ev=e*val
// LDS map (union): main loop Al[64][32]bf16 @0 (4KB), Bl[256][32]bf16 @4096 (16KB)
//                  epilogue  Yl[64][256]bf16 @0 (32KB), Ql[32][256]bf16 @32768 (16KB)
// All tiles use XOR chunk swizzle: chunk c of row r stored at position c ^ f(r)
// (f = (r>>1)&3 for 64B rows, f = r&7 for 512B rows) -> 2-way banks (free) on
// both staging writes and ds_read_b128 fragment reads, and compatible with
// global_load_lds's uniform-base + lane*16 destination rule.
__global__ __launch_bounds__(256) void fused_gemm(
    const float* __restrict__ x, const float* __restrict__ b1,
    const u16* __restrict__ w1t, const u16* __restrict__ qv,
    float* __restrict__ E, float* __restrict__ EV) {
  __shared__ __align__(16) char smem[49152];
  const int t = threadIdx.x;
  const int l = t & 63;
  const int w = __builtin_amdgcn_readfirstlane(t >> 6);
  const int m0 = blockIdx.x * 64;

  // A staging: thread -> (row ar, k-chunk ac); 8 floats -> 8 bf16 -> 1 ds_write_b128
  const int ar = t >> 2;
  const int ac = t & 3;
  const float* xp = x + (size_t)(m0 + ar) * DM + ac * 8;
  char* const aw = smem + ar * 64 + ((ac ^ ((ar >> 1) & 3)) << 4);

  // B staging via global_load_lds: lane fetches the swizzled chunk for its slot
  const int brow = l >> 2;
  const int bcc = (l & 3) ^ ((l >> 3) & 3);
  const u16* wp = w1t + (size_t)(w * 64 + brow) * DM + bcc * 8;

  // fragment read offsets (A[m=lane&15][k=quad*8+j], B[n=lane&15][k=quad*8+j])
  const int lr = l & 15;
  const int q = l >> 4;
  const int coff = ((q ^ ((l >> 1) & 3)) << 4);
  const char* const ard = smem + lr * 64 + coff;
  const char* const brd = smem + 4096 + w * 4096 + lr * 64 + coff;

  f32x4 acc[4][4] = {};

  for (int kt = 0; kt < 64; ++kt) {
    __syncthreads();
    float4 f0 = *(const float4*)xp;
    float4 f1 = *(const float4*)(xp + 4);
    xp += 32;
    union { u16 h[8]; int4 v; } pk;
    pk.h[0] = f2bf(f0.x); pk.h[1] = f2bf(f0.y); pk.h[2] = f2bf(f0.z); pk.h[3] = f2bf(f0.w);
    pk.h[4] = f2bf(f1.x); pk.h[5] = f2bf(f1.y); pk.h[6] = f2bf(f1.z); pk.h[7] = f2bf(f1.w);
    *(int4*)aw = pk.v;
#pragma unroll
    for (int j = 0; j < 4; ++j)
      async16(wp + (size_t)j * 16 * DM, smem + 4096 + (w * 64 + j * 16) * 64);
    wp += 32;
    __syncthreads();
    bf16x8 af[4], bfr[4];
#pragma unroll
    for (int mt = 0; mt < 4; ++mt) af[mt] = *(const bf16x8*)(ard + mt * 1024);
#pragma unroll
    for (int nt = 0; nt < 4; ++nt) bfr[nt] = *(const bf16x8*)(brd + nt * 1024);
#pragma unroll
    for (int mt = 0; mt < 4; ++mt)
#pragma unroll
      for (int nt = 0; nt < 4; ++nt)
        acc[mt][nt] = __builtin_amdgcn_mfma_f32_16x16x32_bf16(af[mt], bfr[nt],
                                                              acc[mt][nt], 0, 0, 0);
  }

  __syncthreads();
  // ---- epilogue 1: bias + relu, write y (bf16) into Yl (swizzled 512B rows)
  float b1v[4];
#pragma unroll
  for (int nt = 0; nt < 4; ++nt) b1v[nt] = b1[w * 64 + nt * 16 + lr];
#pragma unroll
  for (int mt = 0; mt < 4; ++mt)
#pragma unroll
    for (int nt = 0; nt < 4; ++nt) {
      const int nn = w * 64 + nt * 16 + lr;     // D col = lane&15
#pragma unroll
      for (int r = 0; r < 4; ++r) {
        const int m = mt * 16 + q * 4 + r;      // D row = quad*4+reg
        float y = fmaxf(acc[mt][nt][r] + b1v[nt], 0.f);
        *(u16*)(smem + m * 512 + ((((nn >> 3) ^ (m & 7))) << 4) + ((nn & 7) << 1)) = f2bf(y);
      }
    }
  // ---- epilogue 2: stage qv [32][256] bf16 into Ql (same swizzle)
  {
    const int row = t >> 3;
    const int cbase = (t & 7) * 4;
    const u16* src = qv + row * 256 + cbase * 8;
    const int g = row & 7;
#pragma unroll
    for (int i = 0; i < 4; ++i) {
      int4 c = *(const int4*)(src + i * 8);
      *(int4*)(smem + 32768 + row * 512 + (((cbase + i) ^ g) << 4)) = c;
    }
  }
  __syncthreads();
  // ---- epilogue 3: projection MFMA: D2[64m][32c], wave w -> m-tile w
  f32x4 acc2[2] = {};
  {
    const int g = lr & 7;
#pragma unroll
    for (int k2 = 0; k2 < 8; ++k2) {
      const int ck = k2 * 4 + q;
      bf16x8 a = *(const bf16x8*)(smem + (w * 16 + lr) * 512 + ((ck ^ g) << 4));
#pragma unroll
      for (int ct = 0; ct < 2; ++ct) {
        bf16x8 b = *(const bf16x8*)(smem + 32768 + (ct * 16 + lr) * 512 + ((ck ^ g) << 4));
        acc2[ct] = __builtin_amdgcn_mfma_f32_16x16x32_bf16(a, b, acc2[ct], 0, 0, 0);
      }
    }
  }
  // ---- epilogue 4: lane lr holds logit (ct=0) and val (ct=1) for head lr
  {
    const int h = lr;
#pragma unroll
    for (int r = 0; r < 4; ++r) {
      const int token = m0 + w * 16 + q * 4 + r;
      float e = expf(acc2[0][r]);               // global-max shift cancels; |logit|<~0.6
      float ev = e * acc2[1][r];
      E[(size_t)h * NT + token] = e;
      EV[(size_t)h * NT + token] = ev;
    }
  }
}

// ---------------------------------------------------------------------------
// win_kernel: block = (head, 4096-window chunk). Direct 64-sums from LDS,
// thread->window mapping strided by 256 so LDS reads are conflict-free.
__global__ __launch_bounds__(256) void win_kernel(const float* __restrict__ E,
                                                  const float* __restrict__ EV,
                                                  float* __restrict__ pmax) {
  __shared__ float Es[4160];
  __shared__ float Vs[4160];
  __shared__ float red[4];
  const int t = threadIdx.x;
  const int h = blockIdx.x >> 5;
  const int c0 = (blockIdx.x & 31) * 4096;
  const float* Eh = E + (size_t)h * NT;
  const float* Vh = EV + (size_t)h * NT;
  for (int i = t; i < 4160; i += 256) {
    int g = c0 + i;
    bool ok = g < NT;
    Es[i] = ok ? Eh[g] : 1.f;
    Vs[i] = ok ? Vh[g] : 0.f;
  }
  __syncthreads();
  float mx = -1e30f;
  for (int j = 0; j < 16; ++j) {
    int lw = j * 256 + t;
    if (c0 + lw <= NT - WIN) {
      float z = 0.f, wn = 0.f;
#pragma unroll 8
      for (int s = 0; s < WIN; ++s) { z += Es[lw + s]; wn += Vs[lw + s]; }
      mx = fmaxf(mx, wn / z);
    }
  }
#pragma unroll
  for (int off = 32; off; off >>= 1) mx = fmaxf(mx, __shfl_down(mx, off));
  if ((t & 63) == 0) red[t >> 6] = mx;
  __syncthreads();
  if (t == 0) pmax[blockIdx.x] = fmaxf(fmaxf(red[0], red[1]), fmaxf(red[2], red[3]));
}

// ---------------------------------------------------------------------------
__global__ __launch_bounds__(512) void final_kernel(const float* __restrict__ pmax,
                                                    float* __restrict__ out) {
  __shared__ float hm[16];
  const int t = threadIdx.x;                    // 512 = 16 heads * 32 chunks
  float v = pmax[t];
#pragma unroll
  for (int off = 16; off; off >>= 1) v = fmaxf(v, __shfl_down(v, off, 32));
  if ((t & 31) == 0) hm[t >> 5] = v;
  __syncthreads();
  if (t == 0) {
    float s = 0.f;
    for (int i = 0; i < 16; ++i) s += hm[i];
    out[0] = s;
  }
}

// ---------------------------------------------------------------------------
extern "C" void kernel_launch(void* const* d_in, const int* in_sizes, int n_in,
                              void* d_out, int out_size, void* d_ws, size_t ws_size,
                              hipStream_t stream) {
  const float* x       = (const float*)d_in[0];
  const float* w1      = (const float*)d_in[1];
  const float* b1      = (const float*)d_in[2];
  const float* queries = (const float*)d_in[3];
  const float* values  = (const float*)d_in[4];
  // d_in[5] = window_size (fixed 64, compiled in)

  char* ws = (char*)d_ws;
  u16* w1t  = (u16*)ws;                                      // 1 MiB
  u16* qv   = (u16*)(ws + (1u << 20));                       // 16 KiB
  float* E  = (float*)(ws + (1u << 20) + 16384);             // 8 MiB
  float* EV = (float*)(ws + (1u << 20) + 16384 + (size_t)NT * NH * 4);   // 8 MiB
  float* pm = (float*)(ws + (1u << 20) + 16384 + 2 * (size_t)NT * NH * 4); // 2 KiB
  float* out = (float*)d_out;

  prep_kernel<<<2048, 256, 0, stream>>>(w1, queries, values, w1t, qv);
  fused_gemm<<<NT / 64, 256, 0, stream>>>(x, b1, w1t, qv, E, EV);
  win_kernel<<<NH * 32, 256, 0, stream>>>(E, EV, pm);
  final_kernel<<<1, 512, 0, stream>>>(pm, out);
}